// Round 1
// baseline (781.731 us; speedup 1.0000x reference)
//
#include <hip/hip_runtime.h>

// EnhancedReconstructionLoss: loss = 0.8*mean((x-y)^2) + 0.2*(1 - mean(ssim_map))
// ssim from 3x3 avg pools (stride 1, zero-pad 1, divisor always 9).
// Shapes: (32,3,512,512) fp32 -> 96 planes of 512x512.

#define PLANE_H 512
#define PLANE_W 512
#define NPLANES 96
#define TILE    32
#define HALO    34          // TILE + 2
#define LDSW    36          // stride pad: (row*36+col)%32 -> at most 2-way aliasing (free)

static constexpr float kC1   = 0.01f * 0.01f;
static constexpr float kC2   = 0.03f * 0.03f;
static constexpr float kEPS  = 1e-8f;
static constexpr float kINV9 = 1.0f / 9.0f;
static constexpr float kINVN = 1.0f / 25165824.0f;   // 32*3*512*512

__global__ __launch_bounds__(256) void loss_main(
    const float* __restrict__ X, const float* __restrict__ Y,
    float* __restrict__ acc)  // acc[0]=sum (x-y)^2, acc[1]=sum ssim
{
    __shared__ float sx[HALO][LDSW];
    __shared__ float sy[HALO][LDSW];

    const int tid   = threadIdx.x;
    const int tr0   = blockIdx.y * TILE;          // tile row origin in plane
    const int tc0   = blockIdx.x * TILE;          // tile col origin in plane
    const int plane = blockIdx.z;

    const float* __restrict__ xp = X + (size_t)plane * (PLANE_H * PLANE_W);
    const float* __restrict__ yp = Y + (size_t)plane * (PLANE_H * PLANE_W);

    // ---- stage 34x34 halo (zero outside plane) ----
    for (int idx = tid; idx < HALO * HALO; idx += 256) {
        const int hr = idx / HALO;
        const int hc = idx - hr * HALO;
        const int gr = tr0 + hr - 1;
        const int gc = tc0 + hc - 1;
        float vx = 0.0f, vy = 0.0f;
        if ((unsigned)gr < PLANE_H && (unsigned)gc < PLANE_W) {
            const size_t g = (size_t)gr * PLANE_W + (size_t)gc;
            vx = xp[g];
            vy = yp[g];
        }
        sx[hr][hc] = vx;
        sy[hr][hc] = vy;
    }
    __syncthreads();

    // ---- each thread: 4 consecutive output rows at one column ----
    const int tx = tid & 31;        // output col in tile
    const int ty = tid >> 5;        // 0..7
    const int r0 = ty * 4;          // first output row of this thread's strip

    // horizontal 3-tap partials for the 6 LDS rows feeding 4 outputs
    float hx[6], hy[6], hxx[6], hyy[6], hxy[6];
#pragma unroll
    for (int j = 0; j < 6; ++j) {
        const int lr = r0 + j;      // LDS row (= output row r0-1+j in halo coords)
        const float x0 = sx[lr][tx], x1 = sx[lr][tx + 1], x2 = sx[lr][tx + 2];
        const float y0 = sy[lr][tx], y1 = sy[lr][tx + 1], y2 = sy[lr][tx + 2];
        hx[j]  = x0 + x1 + x2;
        hy[j]  = y0 + y1 + y2;
        hxx[j] = x0 * x0 + x1 * x1 + x2 * x2;
        hyy[j] = y0 * y0 + y1 * y1 + y2 * y2;
        hxy[j] = x0 * y0 + x1 * y1 + x2 * y2;
    }

    float mse_acc = 0.0f, ssim_acc = 0.0f;
#pragma unroll
    for (int i = 0; i < 4; ++i) {
        const float s_x  = hx[i]  + hx[i + 1]  + hx[i + 2];
        const float s_y  = hy[i]  + hy[i + 1]  + hy[i + 2];
        const float s_xx = hxx[i] + hxx[i + 1] + hxx[i + 2];
        const float s_yy = hyy[i] + hyy[i + 1] + hyy[i + 2];
        const float s_xy = hxy[i] + hxy[i + 1] + hxy[i + 2];

        const float mu_x = s_x * kINV9;
        const float mu_y = s_y * kINV9;
        const float e_xx = s_xx * kINV9;
        const float e_yy = s_yy * kINV9;
        const float e_xy = s_xy * kINV9;

        const float mu_xx = mu_x * mu_x;
        const float mu_yy = mu_y * mu_y;
        const float mu_xy = mu_x * mu_y;

        const float sig_x = e_xx - mu_xx;
        const float sig_y = e_yy - mu_yy;
        const float sig_xy = e_xy - mu_xy;

        const float num = (2.0f * mu_xy + kC1) * (2.0f * sig_xy + kC2);
        const float den = (mu_xx + mu_yy + kC1) * (sig_x + sig_y + kC2);
        ssim_acc += num / (den + kEPS);

        // MSE: each output pixel maps 1:1 to a plane element (tiles partition plane)
        const float d = sx[r0 + i + 1][tx + 1] - sy[r0 + i + 1][tx + 1];
        mse_acc += d * d;
    }

    // ---- block reduction: wave64 shuffle, then cross-wave via LDS ----
#pragma unroll
    for (int off = 32; off > 0; off >>= 1) {
        mse_acc  += __shfl_down(mse_acc, off, 64);
        ssim_acc += __shfl_down(ssim_acc, off, 64);
    }
    __shared__ float red[8];
    const int wave = tid >> 6;
    if ((tid & 63) == 0) {
        red[wave]     = mse_acc;
        red[4 + wave] = ssim_acc;
    }
    __syncthreads();
    if (tid == 0) {
        const float m = red[0] + red[1] + red[2] + red[3];
        const float s = red[4] + red[5] + red[6] + red[7];
        atomicAdd(&acc[0], m);   // device-scope by default (cross-XCD safe)
        atomicAdd(&acc[1], s);
    }
}

__global__ void loss_final(const float* __restrict__ acc, float* __restrict__ out)
{
    const float mse       = acc[0] * kINVN;
    const float ssim_mean = acc[1] * kINVN;
    out[0] = 0.8f * mse + 0.2f * (1.0f - ssim_mean);
}

extern "C" void kernel_launch(void* const* d_in, const int* in_sizes, int n_in,
                              void* d_out, int out_size, void* d_ws, size_t ws_size,
                              hipStream_t stream)
{
    const float* x = (const float*)d_in[0];   // reconstruction
    const float* y = (const float*)d_in[1];   // target
    float* out = (float*)d_out;
    float* acc = (float*)d_ws;

    hipMemsetAsync(acc, 0, 2 * sizeof(float), stream);

    dim3 grid(PLANE_W / TILE, PLANE_H / TILE, NPLANES);   // 16 x 16 x 96 = 24576 blocks
    loss_main<<<grid, 256, 0, stream>>>(x, y, acc);
    loss_final<<<1, 1, 0, stream>>>(acc, out);
}

// Round 2
// 258.340 us; speedup vs baseline: 3.0260x; 3.0260x over previous
//
#include <hip/hip_runtime.h>

// EnhancedReconstructionLoss: loss = 0.8*mean((x-y)^2) + 0.2*(1 - mean(ssim_map))
// ssim from 3x3 avg pools (stride 1, zero-pad 1, divisor always 9).
// Shapes: (32,3,512,512) fp32 -> 96 planes of 512x512.
//
// R2: replaced the two same-address global atomicAdds per block (49,152
// serialized cross-XCD RMWs ~= the entire 639us of R1) with non-atomic
// per-block partial stores + a second reduction kernel.

#define PLANE_H 512
#define PLANE_W 512
#define NPLANES 96
#define TILE    32
#define HALO    34          // TILE + 2
#define LDSW    36          // stride pad: bank = (4*row + col) % 32 -> worst 2-way (free)
#define NBLOCKS ((PLANE_W / TILE) * (PLANE_H / TILE) * NPLANES)   // 24576

static constexpr float kC1   = 0.01f * 0.01f;
static constexpr float kC2   = 0.03f * 0.03f;
static constexpr float kEPS  = 1e-8f;
static constexpr float kINV9 = 1.0f / 9.0f;
static constexpr float kINVN = 1.0f / 25165824.0f;   // 32*3*512*512

__global__ __launch_bounds__(256) void loss_main(
    const float* __restrict__ X, const float* __restrict__ Y,
    float* __restrict__ part)   // part[bid] = sum(x-y)^2, part[NBLOCKS+bid] = sum ssim
{
    __shared__ float sx[HALO][LDSW];
    __shared__ float sy[HALO][LDSW];

    const int tid   = threadIdx.x;
    const int tr0   = blockIdx.y * TILE;
    const int tc0   = blockIdx.x * TILE;
    const int plane = blockIdx.z;

    const float* __restrict__ xp = X + (size_t)plane * (PLANE_H * PLANE_W);
    const float* __restrict__ yp = Y + (size_t)plane * (PLANE_H * PLANE_W);

    // ---- stage 34x34 halo (zero outside plane) ----
    for (int idx = tid; idx < HALO * HALO; idx += 256) {
        const int hr = idx / HALO;
        const int hc = idx - hr * HALO;
        const int gr = tr0 + hr - 1;
        const int gc = tc0 + hc - 1;
        float vx = 0.0f, vy = 0.0f;
        if ((unsigned)gr < PLANE_H && (unsigned)gc < PLANE_W) {
            const size_t g = (size_t)gr * PLANE_W + (size_t)gc;
            vx = xp[g];
            vy = yp[g];
        }
        sx[hr][hc] = vx;
        sy[hr][hc] = vy;
    }
    __syncthreads();

    // ---- each thread: 4 consecutive output rows at one column ----
    const int tx = tid & 31;
    const int ty = tid >> 5;
    const int r0 = ty * 4;

    float hx[6], hy[6], hxx[6], hyy[6], hxy[6];
#pragma unroll
    for (int j = 0; j < 6; ++j) {
        const int lr = r0 + j;
        const float x0 = sx[lr][tx], x1 = sx[lr][tx + 1], x2 = sx[lr][tx + 2];
        const float y0 = sy[lr][tx], y1 = sy[lr][tx + 1], y2 = sy[lr][tx + 2];
        hx[j]  = x0 + x1 + x2;
        hy[j]  = y0 + y1 + y2;
        hxx[j] = x0 * x0 + x1 * x1 + x2 * x2;
        hyy[j] = y0 * y0 + y1 * y1 + y2 * y2;
        hxy[j] = x0 * y0 + x1 * y1 + x2 * y2;
    }

    float mse_acc = 0.0f, ssim_acc = 0.0f;
#pragma unroll
    for (int i = 0; i < 4; ++i) {
        const float s_x  = hx[i]  + hx[i + 1]  + hx[i + 2];
        const float s_y  = hy[i]  + hy[i + 1]  + hy[i + 2];
        const float s_xx = hxx[i] + hxx[i + 1] + hxx[i + 2];
        const float s_yy = hyy[i] + hyy[i + 1] + hyy[i + 2];
        const float s_xy = hxy[i] + hxy[i + 1] + hxy[i + 2];

        const float mu_x = s_x * kINV9;
        const float mu_y = s_y * kINV9;
        const float e_xx = s_xx * kINV9;
        const float e_yy = s_yy * kINV9;
        const float e_xy = s_xy * kINV9;

        const float mu_xx = mu_x * mu_x;
        const float mu_yy = mu_y * mu_y;
        const float mu_xy = mu_x * mu_y;

        const float sig_x  = e_xx - mu_xx;
        const float sig_y  = e_yy - mu_yy;
        const float sig_xy = e_xy - mu_xy;

        const float num = (2.0f * mu_xy + kC1) * (2.0f * sig_xy + kC2);
        const float den = (mu_xx + mu_yy + kC1) * (sig_x + sig_y + kC2);
        ssim_acc += num / (den + kEPS);

        const float d = sx[r0 + i + 1][tx + 1] - sy[r0 + i + 1][tx + 1];
        mse_acc += d * d;
    }

    // ---- block reduction: wave64 shuffle, then cross-wave via LDS ----
#pragma unroll
    for (int off = 32; off > 0; off >>= 1) {
        mse_acc  += __shfl_down(mse_acc, off, 64);
        ssim_acc += __shfl_down(ssim_acc, off, 64);
    }
    __shared__ float red[8];
    const int wave = tid >> 6;
    if ((tid & 63) == 0) {
        red[wave]     = mse_acc;
        red[4 + wave] = ssim_acc;
    }
    __syncthreads();
    if (tid == 0) {
        const int bid = (blockIdx.z * gridDim.y + blockIdx.y) * gridDim.x + blockIdx.x;
        part[bid]           = red[0] + red[1] + red[2] + red[3];
        part[NBLOCKS + bid] = red[4] + red[5] + red[6] + red[7];
    }
}

__global__ __launch_bounds__(256) void loss_reduce(
    const float* __restrict__ part, float* __restrict__ out)
{
    const int tid = threadIdx.x;
    float m = 0.0f, s = 0.0f;
    for (int i = tid; i < NBLOCKS; i += 256) {
        m += part[i];
        s += part[NBLOCKS + i];
    }
#pragma unroll
    for (int off = 32; off > 0; off >>= 1) {
        m += __shfl_down(m, off, 64);
        s += __shfl_down(s, off, 64);
    }
    __shared__ float red[8];
    const int wave = tid >> 6;
    if ((tid & 63) == 0) {
        red[wave]     = m;
        red[4 + wave] = s;
    }
    __syncthreads();
    if (tid == 0) {
        const float mse       = (red[0] + red[1] + red[2] + red[3]) * kINVN;
        const float ssim_mean = (red[4] + red[5] + red[6] + red[7]) * kINVN;
        out[0] = 0.8f * mse + 0.2f * (1.0f - ssim_mean);
    }
}

extern "C" void kernel_launch(void* const* d_in, const int* in_sizes, int n_in,
                              void* d_out, int out_size, void* d_ws, size_t ws_size,
                              hipStream_t stream)
{
    const float* x = (const float*)d_in[0];   // reconstruction
    const float* y = (const float*)d_in[1];   // target
    float* out  = (float*)d_out;
    float* part = (float*)d_ws;               // needs 2*NBLOCKS*4 = 196,608 B

    dim3 grid(PLANE_W / TILE, PLANE_H / TILE, NPLANES);   // 16 x 16 x 96 = 24576
    loss_main<<<grid, 256, 0, stream>>>(x, y, part);
    loss_reduce<<<1, 256, 0, stream>>>(part, out);
}

// Round 3
// 233.045 us; speedup vs baseline: 3.3544x; 1.1085x over previous
//
#include <hip/hip_runtime.h>

// EnhancedReconstructionLoss: loss = 0.8*mean((x-y)^2) + 0.2*(1 - mean(ssim_map))
// ssim from 3x3 avg pools (stride 1, zero-pad 1, divisor always 9).
// Shapes: (32,3,512,512) fp32 -> 96 planes of 512x512.
//
// R2: atomics -> per-block partial stores (639us -> 101us main).
// R3: (a) single-block reduce (~155us, latency-bound on 1 CU) -> 96-block
//     stage-1 + single-wave final; (b) exact fp32 divide -> v_rcp_f32+mul
//     (saves ~10 VALU insts per SSIM pixel group; error ~1e-7 rel, ok vs
//     0.036 threshold).

#define PLANE_H 512
#define PLANE_W 512
#define NPLANES 96
#define TILE    32
#define HALO    34          // TILE + 2
#define LDSW    36          // stride pad: worst 2-way bank aliasing (free per m136)
#define NBLOCKS ((PLANE_W / TILE) * (PLANE_H / TILE) * NPLANES)   // 24576
#define NB1     (NBLOCKS / 256)                                    // 96 stage-1 blocks

static constexpr float kC1   = 0.01f * 0.01f;
static constexpr float kC2   = 0.03f * 0.03f;
static constexpr float kEPS  = 1e-8f;
static constexpr float kINV9 = 1.0f / 9.0f;
static constexpr float kINVN = 1.0f / 25165824.0f;   // 32*3*512*512

__global__ __launch_bounds__(256) void loss_main(
    const float* __restrict__ X, const float* __restrict__ Y,
    float* __restrict__ part)   // part[bid]=sum(x-y)^2, part[NBLOCKS+bid]=sum ssim
{
    __shared__ float sx[HALO][LDSW];
    __shared__ float sy[HALO][LDSW];

    const int tid   = threadIdx.x;
    const int tr0   = blockIdx.y * TILE;
    const int tc0   = blockIdx.x * TILE;
    const int plane = blockIdx.z;

    const float* __restrict__ xp = X + (size_t)plane * (PLANE_H * PLANE_W);
    const float* __restrict__ yp = Y + (size_t)plane * (PLANE_H * PLANE_W);

    // ---- stage 34x34 halo (zero outside plane) ----
    for (int idx = tid; idx < HALO * HALO; idx += 256) {
        const int hr = idx / HALO;
        const int hc = idx - hr * HALO;
        const int gr = tr0 + hr - 1;
        const int gc = tc0 + hc - 1;
        float vx = 0.0f, vy = 0.0f;
        if ((unsigned)gr < PLANE_H && (unsigned)gc < PLANE_W) {
            const size_t g = (size_t)gr * PLANE_W + (size_t)gc;
            vx = xp[g];
            vy = yp[g];
        }
        sx[hr][hc] = vx;
        sy[hr][hc] = vy;
    }
    __syncthreads();

    // ---- each thread: 4 consecutive output rows at one column ----
    const int tx = tid & 31;
    const int ty = tid >> 5;
    const int r0 = ty * 4;

    float hx[6], hy[6], hxx[6], hyy[6], hxy[6];
#pragma unroll
    for (int j = 0; j < 6; ++j) {
        const int lr = r0 + j;
        const float x0 = sx[lr][tx], x1 = sx[lr][tx + 1], x2 = sx[lr][tx + 2];
        const float y0 = sy[lr][tx], y1 = sy[lr][tx + 1], y2 = sy[lr][tx + 2];
        hx[j]  = x0 + x1 + x2;
        hy[j]  = y0 + y1 + y2;
        hxx[j] = x0 * x0 + x1 * x1 + x2 * x2;
        hyy[j] = y0 * y0 + y1 * y1 + y2 * y2;
        hxy[j] = x0 * y0 + x1 * y1 + x2 * y2;
    }

    float mse_acc = 0.0f, ssim_acc = 0.0f;
#pragma unroll
    for (int i = 0; i < 4; ++i) {
        const float s_x  = hx[i]  + hx[i + 1]  + hx[i + 2];
        const float s_y  = hy[i]  + hy[i + 1]  + hy[i + 2];
        const float s_xx = hxx[i] + hxx[i + 1] + hxx[i + 2];
        const float s_yy = hyy[i] + hyy[i + 1] + hyy[i + 2];
        const float s_xy = hxy[i] + hxy[i + 1] + hxy[i + 2];

        const float mu_x = s_x * kINV9;
        const float mu_y = s_y * kINV9;
        const float e_xx = s_xx * kINV9;
        const float e_yy = s_yy * kINV9;
        const float e_xy = s_xy * kINV9;

        const float mu_xx = mu_x * mu_x;
        const float mu_yy = mu_y * mu_y;
        const float mu_xy = mu_x * mu_y;

        const float sig_x  = e_xx - mu_xx;
        const float sig_y  = e_yy - mu_yy;
        const float sig_xy = e_xy - mu_xy;

        const float num = (2.0f * mu_xy + kC1) * (2.0f * sig_xy + kC2);
        const float den = (mu_xx + mu_yy + kC1) * (sig_x + sig_y + kC2) + kEPS;
        // v_rcp_f32 (~1ulp) + mul instead of exact divide (div_scale/fmas/fixup)
        ssim_acc += num * __builtin_amdgcn_rcpf(den);

        const float d = sx[r0 + i + 1][tx + 1] - sy[r0 + i + 1][tx + 1];
        mse_acc += d * d;
    }

    // ---- block reduction: wave64 shuffle, then cross-wave via LDS ----
#pragma unroll
    for (int off = 32; off > 0; off >>= 1) {
        mse_acc  += __shfl_down(mse_acc, off, 64);
        ssim_acc += __shfl_down(ssim_acc, off, 64);
    }
    __shared__ float red[8];
    const int wave = tid >> 6;
    if ((tid & 63) == 0) {
        red[wave]     = mse_acc;
        red[4 + wave] = ssim_acc;
    }
    __syncthreads();
    if (tid == 0) {
        const int bid = (blockIdx.z * gridDim.y + blockIdx.y) * gridDim.x + blockIdx.x;
        part[bid]           = red[0] + red[1] + red[2] + red[3];
        part[NBLOCKS + bid] = red[4] + red[5] + red[6] + red[7];
    }
}

// Stage-1 reduce: 96 blocks x 256 threads, one element per thread, coalesced.
__global__ __launch_bounds__(256) void loss_reduce1(
    const float* __restrict__ part, float* __restrict__ part2)
{
    const int tid = threadIdx.x;
    const int i   = blockIdx.x * 256 + tid;
    float m = part[i];
    float s = part[NBLOCKS + i];
#pragma unroll
    for (int off = 32; off > 0; off >>= 1) {
        m += __shfl_down(m, off, 64);
        s += __shfl_down(s, off, 64);
    }
    __shared__ float red[8];
    const int wave = tid >> 6;
    if ((tid & 63) == 0) {
        red[wave]     = m;
        red[4 + wave] = s;
    }
    __syncthreads();
    if (tid == 0) {
        part2[blockIdx.x]       = red[0] + red[1] + red[2] + red[3];
        part2[NB1 + blockIdx.x] = red[4] + red[5] + red[6] + red[7];
    }
}

// Final: one wave sums the 96+96 stage-1 partials.
__global__ __launch_bounds__(64) void loss_final(
    const float* __restrict__ part2, float* __restrict__ out)
{
    const int tid = threadIdx.x;
    float m = 0.0f, s = 0.0f;
    for (int i = tid; i < NB1; i += 64) {   // 96/64 -> 2 iters (second partial)
        m += part2[i];
        s += part2[NB1 + i];
    }
#pragma unroll
    for (int off = 32; off > 0; off >>= 1) {
        m += __shfl_down(m, off, 64);
        s += __shfl_down(s, off, 64);
    }
    if (tid == 0) {
        const float mse       = m * kINVN;
        const float ssim_mean = s * kINVN;
        out[0] = 0.8f * mse + 0.2f * (1.0f - ssim_mean);
    }
}

extern "C" void kernel_launch(void* const* d_in, const int* in_sizes, int n_in,
                              void* d_out, int out_size, void* d_ws, size_t ws_size,
                              hipStream_t stream)
{
    const float* x = (const float*)d_in[0];   // reconstruction
    const float* y = (const float*)d_in[1];   // target
    float* out   = (float*)d_out;
    float* part  = (float*)d_ws;                      // 2*NBLOCKS floats
    float* part2 = part + 2 * NBLOCKS;                // 2*NB1 floats

    dim3 grid(PLANE_W / TILE, PLANE_H / TILE, NPLANES);   // 16 x 16 x 96
    loss_main<<<grid, 256, 0, stream>>>(x, y, part);
    loss_reduce1<<<NB1, 256, 0, stream>>>(part, part2);
    loss_final<<<1, 64, 0, stream>>>(part2, out);
}

// Round 4
// 226.099 us; speedup vs baseline: 3.4575x; 1.0307x over previous
//
#include <hip/hip_runtime.h>

// EnhancedReconstructionLoss: loss = 0.8*mean((x-y)^2) + 0.2*(1 - mean(ssim_map))
// ssim from 3x3 avg pools (stride 1, zero-pad 1, divisor always 9).
// Shapes: (32,3,512,512) fp32 -> 96 planes of 512x512.
//
// R2: atomics -> per-block partial stores (639 -> 101 us main).
// R3: parallel 2-stage reduce; rcp instead of divide (96 us main). Found
//     main<->total gap ~140us is fixed harness overhead, not our kernels.
// R4: loss_main was VALU-issue-bound (186 inst/pixel at 4 px/thread).
//     64x64 tile, 16 px/thread (4x4 patch): 4x fewer waves, float4+b128
//     staging, b64 LDS reads, scaled-domain SSIM (fold /9,/81 into consts).

#define PLANE_H 512
#define PLANE_W 512
#define NPLANES 96
#define TILE_W  64
#define TILE_H  64
#define LDSH    66                 // TILE_H + 2 halo rows
#define LDSW    76                 // floats/row staged; 304 B = 16B multiple
#define NF4     (LDSH * (LDSW/4))  // 1254 float4 per array per tile
#define NBLOCKS ((PLANE_W / TILE_W) * (PLANE_H / TILE_H) * NPLANES)   // 6144
#define NB1     (NBLOCKS / 256)    // 24

static constexpr float kC1s  = 81.0f * 0.0001f;   // 81*C1
static constexpr float kC2s  = 81.0f * 0.0009f;   // 81*C2
static constexpr float kEPSs = 6561.0f * 1e-8f;   // 81^2*eps
static constexpr float kINVN = 1.0f / 25165824.0f;

__global__ __launch_bounds__(256, 4) void loss_main(
    const float* __restrict__ X, const float* __restrict__ Y,
    float* __restrict__ part)
{
    __shared__ __align__(16) float sx[LDSH][LDSW];
    __shared__ __align__(16) float sy[LDSH][LDSW];

    const int tid   = threadIdx.x;
    const int tr0   = blockIdx.y * TILE_H;
    const int tc0   = blockIdx.x * TILE_W;
    const int plane = blockIdx.z;

    const float* __restrict__ xp = X + (size_t)plane * (PLANE_H * PLANE_W);
    const float* __restrict__ yp = Y + (size_t)plane * (PLANE_H * PLANE_W);

    // ---- stage halo: rows [tr0-1, tr0+65), cols [tc0-4, tc0+72) as float4 ----
    // Boundary quads are fully in-plane or fully out (tc0 % 64 == 0), so
    // predicate per-quad and zero-fill out-of-plane (matches zero padding).
    for (int i = tid; i < NF4; i += 256) {
        const int hr = i / (LDSW / 4);
        const int hq = i - hr * (LDSW / 4);
        const int gr = tr0 - 1 + hr;
        const int gc = tc0 - 4 + 4 * hq;
        float4 vx = make_float4(0.f, 0.f, 0.f, 0.f);
        float4 vy = make_float4(0.f, 0.f, 0.f, 0.f);
        if ((unsigned)gr < PLANE_H && (unsigned)gc < PLANE_W) {
            const size_t g = (size_t)gr * PLANE_W + (size_t)gc;
            vx = *(const float4*)(xp + g);
            vy = *(const float4*)(yp + g);
        }
        *(float4*)&sx[hr][4 * hq] = vx;
        *(float4*)&sy[hr][4 * hq] = vy;
    }
    __syncthreads();

    // ---- each thread: 4x4 pixel patch ----
    // pixel (pr, pc) -> global (tr0+pr, tc0+pc); LDS row = pr+1, LDS col = pc+4.
    const int pc0 = (tid & 15) * 4;   // 0..60
    const int pr0 = (tid >> 4) * 4;   // 0..60

    float h0[5][4], h1[5][4];   // h-partial rows j-2, j-1 (x, y, xx, yy, xy)
    float xm[4], ym[4];         // row j-1 center elements (for MSE)
    float mse_acc = 0.0f, ssim_acc = 0.0f;

#pragma unroll
    for (int j = 0; j < 6; ++j) {
        const int R = pr0 + j;        // LDS row (pixel row pr0-1+j)

        // read 8 floats per array: LDS cols pc0+2 .. pc0+9 (= pixel cols pc0-2..pc0+5)
        float fx[8], fy[8];
#pragma unroll
        for (int u = 0; u < 4; ++u) {
            const float2 a = *(const float2*)&sx[R][pc0 + 2 + 2 * u];
            const float2 b = *(const float2*)&sy[R][pc0 + 2 + 2 * u];
            fx[2 * u] = a.x; fx[2 * u + 1] = a.y;
            fy[2 * u] = b.x; fy[2 * u + 1] = b.y;
        }

        // products once per element (pixel cols pc0-1 .. pc0+4 = fx[1..6])
        float xx[6], yy[6], xy[6];
#pragma unroll
        for (int m = 0; m < 6; ++m) {
            const float a = fx[m + 1], b = fy[m + 1];
            xx[m] = a * a; yy[m] = b * b; xy[m] = a * b;
        }

        // horizontal 3-tap partials for the 4 pixel columns
        float hc[5][4];
#pragma unroll
        for (int q = 0; q < 4; ++q) {
            hc[0][q] = fx[q + 1] + fx[q + 2] + fx[q + 3];
            hc[1][q] = fy[q + 1] + fy[q + 2] + fy[q + 3];
            hc[2][q] = xx[q] + xx[q + 1] + xx[q + 2];
            hc[3][q] = yy[q] + yy[q + 1] + yy[q + 2];
            hc[4][q] = xy[q] + xy[q + 1] + xy[q + 2];
        }

        // emit pixel row pr0 + (j-2) once 3 h-rows are available
        if (j >= 2) {
#pragma unroll
            for (int q = 0; q < 4; ++q) {
                const float s_x  = h0[0][q] + h1[0][q] + hc[0][q];
                const float s_y  = h0[1][q] + h1[1][q] + hc[1][q];
                const float s_xx = h0[2][q] + h1[2][q] + hc[2][q];
                const float s_yy = h0[3][q] + h1[3][q] + hc[3][q];
                const float s_xy = h0[4][q] + h1[4][q] + hc[4][q];

                // scaled-domain SSIM: mu=s/9, everything x81; 81^2 cancels in ratio
                const float P   = s_x * s_y;
                const float Q   = s_x * s_x + s_y * s_y;
                const float t1  = 2.0f * P + kC1s;
                const float t2  = 9.0f * s_xy - P;
                const float t3  = 2.0f * t2 + kC2s;
                const float num = t1 * t3;
                const float u1  = Q + kC1s;
                const float u2  = 9.0f * (s_xx + s_yy) - Q;   // >= 0 (Cauchy-Schwarz)
                const float den = u1 * (u2 + kC2s) + kEPSs;   // > 0 always
                ssim_acc += num * __builtin_amdgcn_rcpf(den);

                const float d = xm[q] - ym[q];
                mse_acc += d * d;
            }
        }

        // rotate h-rows, stash center elements of current row for next emit
#pragma unroll
        for (int t = 0; t < 5; ++t)
#pragma unroll
            for (int q = 0; q < 4; ++q) {
                h0[t][q] = h1[t][q];
                h1[t][q] = hc[t][q];
            }
#pragma unroll
        for (int q = 0; q < 4; ++q) { xm[q] = fx[q + 2]; ym[q] = fy[q + 2]; }
    }

    // ---- block reduction ----
#pragma unroll
    for (int off = 32; off > 0; off >>= 1) {
        mse_acc  += __shfl_down(mse_acc, off, 64);
        ssim_acc += __shfl_down(ssim_acc, off, 64);
    }
    __shared__ float red[8];
    const int wave = tid >> 6;
    if ((tid & 63) == 0) {
        red[wave]     = mse_acc;
        red[4 + wave] = ssim_acc;
    }
    __syncthreads();
    if (tid == 0) {
        const int bid = (blockIdx.z * gridDim.y + blockIdx.y) * gridDim.x + blockIdx.x;
        part[bid]           = red[0] + red[1] + red[2] + red[3];
        part[NBLOCKS + bid] = red[4] + red[5] + red[6] + red[7];
    }
}

__global__ __launch_bounds__(256) void loss_reduce1(
    const float* __restrict__ part, float* __restrict__ part2)
{
    const int tid = threadIdx.x;
    const int i   = blockIdx.x * 256 + tid;
    float m = part[i];
    float s = part[NBLOCKS + i];
#pragma unroll
    for (int off = 32; off > 0; off >>= 1) {
        m += __shfl_down(m, off, 64);
        s += __shfl_down(s, off, 64);
    }
    __shared__ float red[8];
    const int wave = tid >> 6;
    if ((tid & 63) == 0) {
        red[wave]     = m;
        red[4 + wave] = s;
    }
    __syncthreads();
    if (tid == 0) {
        part2[blockIdx.x]       = red[0] + red[1] + red[2] + red[3];
        part2[NB1 + blockIdx.x] = red[4] + red[5] + red[6] + red[7];
    }
}

__global__ __launch_bounds__(64) void loss_final(
    const float* __restrict__ part2, float* __restrict__ out)
{
    const int tid = threadIdx.x;
    float m = 0.0f, s = 0.0f;
    if (tid < NB1) {
        m = part2[tid];
        s = part2[NB1 + tid];
    }
#pragma unroll
    for (int off = 32; off > 0; off >>= 1) {
        m += __shfl_down(m, off, 64);
        s += __shfl_down(s, off, 64);
    }
    if (tid == 0) {
        const float mse       = m * kINVN;
        const float ssim_mean = s * kINVN;
        out[0] = 0.8f * mse + 0.2f * (1.0f - ssim_mean);
    }
}

extern "C" void kernel_launch(void* const* d_in, const int* in_sizes, int n_in,
                              void* d_out, int out_size, void* d_ws, size_t ws_size,
                              hipStream_t stream)
{
    const float* x = (const float*)d_in[0];   // reconstruction
    const float* y = (const float*)d_in[1];   // target
    float* out   = (float*)d_out;
    float* part  = (float*)d_ws;              // 2*NBLOCKS floats
    float* part2 = part + 2 * NBLOCKS;        // 2*NB1 floats

    dim3 grid(PLANE_W / TILE_W, PLANE_H / TILE_H, NPLANES);   // 8 x 8 x 96
    loss_main<<<grid, 256, 0, stream>>>(x, y, part);
    loss_reduce1<<<NB1, 256, 0, stream>>>(part, part2);
    loss_final<<<1, 64, 0, stream>>>(part2, out);
}